// Round 3
// baseline (390.952 us; speedup 1.0000x reference)
//
#include <hip/hip_runtime.h>
#include <hip/hip_bf16.h>

#define T_DIM 4096
#define B_DIM 16
#define C_DIM 512
#define H_DIM 128
#define M_DIM (T_DIM * B_DIM)   // 65536 rows

// ---------------- GEMM: v = sigmoid(x@Bw^T + Bb) * (x@Uw^T + Ub) ----------------
// 512 threads = 8 waves, arranged 4(M) x 2(N). Wave tile 32M x 64N, dual gate.
// acc = 2*2*4 floatx4 = 64 VGPRs/thread -> no spill under (512,1).

#define BM 128
#define BK 32
#define LDK 40   // padded LDS row stride (bf16 elems)

using floatx4 = __attribute__((ext_vector_type(4))) float;
using bf16x8  = __attribute__((ext_vector_type(8))) __bf16;

union bfpack { ushort4 u4; __hip_bfloat16 b[4]; };

__global__ __launch_bounds__(512, 1) void gemm_gates(
    const float* __restrict__ x, const float* __restrict__ Uw,
    const float* __restrict__ Ub, const float* __restrict__ Bw,
    const float* __restrict__ Bb, float* __restrict__ v)
{
    __shared__ __bf16 As[BM * LDK];    // 10240 B
    __shared__ __bf16 Ws[256 * LDK];   // 20480 B (rows 0..127 = Uw, 128..255 = Bw)

    const int tid  = threadIdx.x;
    const int wid  = tid >> 6;
    const int lane = tid & 63;
    const int m0   = blockIdx.x * BM;

    const int wm = (wid >> 1) * 32;   // 4 M-groups of 32
    const int wn = (wid & 1) * 64;    // 2 N-groups of 64
    const int row = lane & 15;
    const int q   = lane >> 4;

    floatx4 acc_u[2][4], acc_b[2][4];
    const floatx4 fzero = {0.f, 0.f, 0.f, 0.f};
#pragma unroll
    for (int mt = 0; mt < 2; ++mt)
#pragma unroll
        for (int nt = 0; nt < 4; ++nt) { acc_u[mt][nt] = fzero; acc_b[mt][nt] = fzero; }

    for (int ks = 0; ks < C_DIM / BK; ++ks) {
        const int k0 = ks * BK;
        __syncthreads();
        // stage x tile: 128 rows x 32 fp32 -> bf16 (1024 float4 slots / 512 thr)
#pragma unroll
        for (int it = 0; it < 2; ++it) {
            int idx = tid + it * 512;
            int r = idx >> 3, c4 = (idx & 7) * 4;
            const float4 f = *(const float4*)(x + (size_t)(m0 + r) * C_DIM + k0 + c4);
            bfpack pk;
            pk.b[0] = __float2bfloat16(f.x); pk.b[1] = __float2bfloat16(f.y);
            pk.b[2] = __float2bfloat16(f.z); pk.b[3] = __float2bfloat16(f.w);
            *(ushort4*)&As[r * LDK + c4] = pk.u4;
        }
        // stage W tile: 256 rows x 32 fp32 -> bf16 (2048 slots / 512 thr)
#pragma unroll
        for (int it = 0; it < 4; ++it) {
            int idx = tid + it * 512;
            int r = idx >> 3, c4 = (idx & 7) * 4;
            const float* src = (r < 128) ? (Uw + (size_t)r * C_DIM)
                                         : (Bw + (size_t)(r - 128) * C_DIM);
            const float4 f = *(const float4*)(src + k0 + c4);
            bfpack pk;
            pk.b[0] = __float2bfloat16(f.x); pk.b[1] = __float2bfloat16(f.y);
            pk.b[2] = __float2bfloat16(f.z); pk.b[3] = __float2bfloat16(f.w);
            *(ushort4*)&Ws[r * LDK + c4] = pk.u4;
        }
        __syncthreads();

        bf16x8 afr[2], ufr[4], bfr[4];
#pragma unroll
        for (int mt = 0; mt < 2; ++mt)
            afr[mt] = *(const bf16x8*)&As[(wm + mt * 16 + row) * LDK + q * 8];
#pragma unroll
        for (int nt = 0; nt < 4; ++nt) {
            ufr[nt] = *(const bf16x8*)&Ws[(wn + nt * 16 + row) * LDK + q * 8];
            bfr[nt] = *(const bf16x8*)&Ws[(128 + wn + nt * 16 + row) * LDK + q * 8];
        }
#pragma unroll
        for (int mt = 0; mt < 2; ++mt)
#pragma unroll
            for (int nt = 0; nt < 4; ++nt) {
                acc_u[mt][nt] = __builtin_amdgcn_mfma_f32_16x16x32_bf16(
                    afr[mt], ufr[nt], acc_u[mt][nt], 0, 0, 0);
                acc_b[mt][nt] = __builtin_amdgcn_mfma_f32_16x16x32_bf16(
                    afr[mt], bfr[nt], acc_b[mt][nt], 0, 0, 0);
            }
    }

#pragma unroll
    for (int nt = 0; nt < 4; ++nt) {
        const int h = wn + nt * 16 + row;
        const float ub = Ub[h], bb = Bb[h];
#pragma unroll
        for (int mt = 0; mt < 2; ++mt) {
#pragma unroll
            for (int r = 0; r < 4; ++r) {
                const int m = m0 + wm + mt * 16 + q * 4 + r;
                const float uu = acc_u[mt][nt][r] + ub;
                const float gg = acc_b[mt][nt][r] + bb;
                v[(size_t)m * H_DIM + h] = uu / (1.f + __expf(-gg));
            }
        }
    }
}

// ---------------- Recurrence: wave-per-chain, zero barriers, A pinned in VGPRs --
// One 64-lane wave owns one (chunk, b) chain. Lane l owns rows l and l+64.
// A rows are PINNED in 256 VGPRs via empty inline-asm (defeats the compiler's
// rematerialization that was re-loading A from L2 every step in R1/R2).
// h broadcast through per-wave LDS (intra-wave: lgkmcnt only, no s_barrier).

#define CHUNK_L 64
#define WARM_K  32

__global__ __launch_bounds__(256, 1) void recur_kernel(
    const float* __restrict__ v, const float* __restrict__ A,
    float* __restrict__ out)
{
    const int tid  = threadIdx.x;
    const int wid  = tid >> 6;
    const int lane = tid & 63;
    const int cid   = blockIdx.x * 4 + wid;   // 0..1023
    const int chunk = cid >> 4;               // 0..63
    const int b     = cid & 15;
    const int r0    = lane;
    const int r1    = lane + 64;

    __shared__ float hs[4][H_DIM];
    float* h = hs[wid];

    // A rows -> registers, then PIN so they stay in VGPRs
    float a0[H_DIM], a1[H_DIM];
    {
        const float4* A0 = (const float4*)(A + (size_t)r0 * H_DIM);
        const float4* A1 = (const float4*)(A + (size_t)r1 * H_DIM);
#pragma unroll
        for (int jj = 0; jj < 32; ++jj) {
            float4 f0 = A0[jj], f1 = A1[jj];
            a0[4*jj+0] = f0.x; a0[4*jj+1] = f0.y; a0[4*jj+2] = f0.z; a0[4*jj+3] = f0.w;
            a1[4*jj+0] = f1.x; a1[4*jj+1] = f1.y; a1[4*jj+2] = f1.z; a1[4*jj+3] = f1.w;
        }
    }
#pragma unroll
    for (int j = 0; j < H_DIM; ++j) {
        asm("" : "+v"(a0[j]));
        asm("" : "+v"(a1[j]));
    }

    h[r0] = 0.f;
    h[r1] = 0.f;

    const int tout = chunk * CHUNK_L;
    const int ts   = (tout - WARM_K < 0) ? 0 : tout - WARM_K;
    const int tend = tout + CHUNK_L;

    // rotating 2-deep prefetch of v
    float pv0[2], pv1[2];
    {
        const size_t base0 = (size_t)(ts * B_DIM + b) * H_DIM;
        const size_t base1 = (size_t)((ts + 1) * B_DIM + b) * H_DIM;
        pv0[0] = v[base0 + r0]; pv1[0] = v[base0 + r1];
        pv0[1] = v[base1 + r0]; pv1[1] = v[base1 + r1];
    }

#pragma unroll 2
    for (int t = ts; t < tend; ++t) {
        const int slot = t & 1;
        const float cur0 = pv0[slot];
        const float cur1 = pv1[slot];
        if (t + 2 < tend) {
            const size_t basep = (size_t)((t + 2) * B_DIM + b) * H_DIM;
            pv0[slot] = v[basep + r0];
            pv1[slot] = v[basep + r1];
        }

        float s00 = cur0, s01 = 0.f, s02 = 0.f, s03 = 0.f;
        float s10 = cur1, s11 = 0.f, s12 = 0.f, s13 = 0.f;
        const float4* h4 = (const float4*)h;
#pragma unroll
        for (int jj = 0; jj < 32; ++jj) {
            const float4 hv = h4[jj];
            s00 += a0[4*jj+0] * hv.x; s01 += a0[4*jj+1] * hv.y;
            s02 += a0[4*jj+2] * hv.z; s03 += a0[4*jj+3] * hv.w;
            s10 += a1[4*jj+0] * hv.x; s11 += a1[4*jj+1] * hv.y;
            s12 += a1[4*jj+2] * hv.z; s13 += a1[4*jj+3] * hv.w;
        }
        const float hn0 = (s00 + s01) + (s02 + s03);
        const float hn1 = (s10 + s11) + (s12 + s13);

        h[r0] = hn0;
        h[r1] = hn1;

        if (t >= tout) {
            const size_t ob = (size_t)(t * B_DIM + b) * H_DIM;
            out[ob + r0] = hn0;
            out[ob + r1] = hn1;
        }
    }
}

// ------------------------------------------------------------------------------

extern "C" void kernel_launch(void* const* d_in, const int* in_sizes, int n_in,
                              void* d_out, int out_size, void* d_ws, size_t ws_size,
                              hipStream_t stream) {
    const float* x  = (const float*)d_in[0];
    const float* Uw = (const float*)d_in[1];
    const float* Ub = (const float*)d_in[2];
    const float* Bw = (const float*)d_in[3];
    const float* Bb = (const float*)d_in[4];
    const float* Aw = (const float*)d_in[5];
    float* out = (float*)d_out;
    float* vbuf = (float*)d_ws;   // T*B*H fp32 = 32 MiB

    gemm_gates<<<M_DIM / BM, 512, 0, stream>>>(x, Uw, Ub, Bw, Bb, vbuf);
    recur_kernel<<<(T_DIM / CHUNK_L) * B_DIM / 4, 256, 0, stream>>>(vbuf, Aw, out);
}

// Round 4
// 286.330 us; speedup vs baseline: 1.3654x; 1.3654x over previous
//
#include <hip/hip_runtime.h>
#include <hip/hip_bf16.h>

#define T_DIM 4096
#define B_DIM 16
#define C_DIM 512
#define H_DIM 128
#define M_DIM (T_DIM * B_DIM)   // 65536 rows

using floatx4 = __attribute__((ext_vector_type(4))) float;
using bf16x8  = __attribute__((ext_vector_type(8))) __bf16;

// ---------------- GEMM: v = sigmoid(x@Bw^T + Bb) * (x@Uw^T + Ub) ----------------
#define BM 128
#define BK 32
#define LDK 40

union bfpack { ushort4 u4; __hip_bfloat16 b[4]; };

__global__ __launch_bounds__(512, 1) void gemm_gates(
    const float* __restrict__ x, const float* __restrict__ Uw,
    const float* __restrict__ Ub, const float* __restrict__ Bw,
    const float* __restrict__ Bb, float* __restrict__ v)
{
    __shared__ __bf16 As[BM * LDK];
    __shared__ __bf16 Ws[256 * LDK];   // rows 0..127 = Uw, 128..255 = Bw

    const int tid  = threadIdx.x;
    const int wid  = tid >> 6;
    const int lane = tid & 63;
    const int m0   = blockIdx.x * BM;

    const int wm = (wid >> 1) * 32;
    const int wn = (wid & 1) * 64;
    const int row = lane & 15;
    const int q   = lane >> 4;

    floatx4 acc_u[2][4], acc_b[2][4];
    const floatx4 fzero = {0.f, 0.f, 0.f, 0.f};
#pragma unroll
    for (int mt = 0; mt < 2; ++mt)
#pragma unroll
        for (int nt = 0; nt < 4; ++nt) { acc_u[mt][nt] = fzero; acc_b[mt][nt] = fzero; }

    for (int ks = 0; ks < C_DIM / BK; ++ks) {
        const int k0 = ks * BK;
        __syncthreads();
#pragma unroll
        for (int it = 0; it < 2; ++it) {
            int idx = tid + it * 512;
            int r = idx >> 3, c4 = (idx & 7) * 4;
            const float4 f = *(const float4*)(x + (size_t)(m0 + r) * C_DIM + k0 + c4);
            bfpack pk;
            pk.b[0] = __float2bfloat16(f.x); pk.b[1] = __float2bfloat16(f.y);
            pk.b[2] = __float2bfloat16(f.z); pk.b[3] = __float2bfloat16(f.w);
            *(ushort4*)&As[r * LDK + c4] = pk.u4;
        }
#pragma unroll
        for (int it = 0; it < 4; ++it) {
            int idx = tid + it * 512;
            int r = idx >> 3, c4 = (idx & 7) * 4;
            const float* src = (r < 128) ? (Uw + (size_t)r * C_DIM)
                                         : (Bw + (size_t)(r - 128) * C_DIM);
            const float4 f = *(const float4*)(src + k0 + c4);
            bfpack pk;
            pk.b[0] = __float2bfloat16(f.x); pk.b[1] = __float2bfloat16(f.y);
            pk.b[2] = __float2bfloat16(f.z); pk.b[3] = __float2bfloat16(f.w);
            *(ushort4*)&Ws[r * LDK + c4] = pk.u4;
        }
        __syncthreads();

        bf16x8 afr[2], ufr[4], bfr[4];
#pragma unroll
        for (int mt = 0; mt < 2; ++mt)
            afr[mt] = *(const bf16x8*)&As[(wm + mt * 16 + row) * LDK + q * 8];
#pragma unroll
        for (int nt = 0; nt < 4; ++nt) {
            ufr[nt] = *(const bf16x8*)&Ws[(wn + nt * 16 + row) * LDK + q * 8];
            bfr[nt] = *(const bf16x8*)&Ws[(128 + wn + nt * 16 + row) * LDK + q * 8];
        }
#pragma unroll
        for (int mt = 0; mt < 2; ++mt)
#pragma unroll
            for (int nt = 0; nt < 4; ++nt) {
                acc_u[mt][nt] = __builtin_amdgcn_mfma_f32_16x16x32_bf16(
                    afr[mt], ufr[nt], acc_u[mt][nt], 0, 0, 0);
                acc_b[mt][nt] = __builtin_amdgcn_mfma_f32_16x16x32_bf16(
                    afr[mt], bfr[nt], acc_b[mt][nt], 0, 0, 0);
            }
    }

#pragma unroll
    for (int nt = 0; nt < 4; ++nt) {
        const int h = wn + nt * 16 + row;
        const float ub = Ub[h], bb = Bb[h];
#pragma unroll
        for (int mt = 0; mt < 2; ++mt) {
#pragma unroll
            for (int r = 0; r < 4; ++r) {
                const int m = m0 + wm + mt * 16 + q * 4 + r;
                const float uu = acc_u[mt][nt][r] + ub;
                const float gg = acc_b[mt][nt][r] + bb;
                v[(size_t)m * H_DIM + h] = uu / (1.f + __expf(-gg));
            }
        }
    }
}

// ---------------- Recurrence via MFMA: h' = A@h + v_t, one wave per chunk ------
// Wave handles all 16 batches. A held as 32 bf16x8 MFMA A-fragments (registers/
// AGPRs — no scalar-array spill path). h round-trips through a small padded LDS
// buffer (bf16) to convert C/D layout -> B-operand layout. Intra-wave only: no
// barriers. v_t enters as the fp32 C operand, prefetched one step ahead.

#define CHUNK_L 32
#define WARM_K  32
#define HS 272   // bytes per batch row in hbuf (128 bf16 = 256 B + 16 pad)

#define MFMA16(a, b, c) __builtin_amdgcn_mfma_f32_16x16x32_bf16(a, b, c, 0, 0, 0)

union AFu { bf16x8 v; __hip_bfloat16 h[8]; };

#define LOADAF(MT, KT, DST) { \
    const float* p = A + ((MT) * 16 + m) * H_DIM + (KT) * 32 + q * 8; \
    const float4 f0 = *(const float4*)p; \
    const float4 f1 = *(const float4*)(p + 4); \
    AFu u_; \
    u_.h[0] = __float2bfloat16(f0.x); u_.h[1] = __float2bfloat16(f0.y); \
    u_.h[2] = __float2bfloat16(f0.z); u_.h[3] = __float2bfloat16(f0.w); \
    u_.h[4] = __float2bfloat16(f1.x); u_.h[5] = __float2bfloat16(f1.y); \
    u_.h[6] = __float2bfloat16(f1.z); u_.h[7] = __float2bfloat16(f1.w); \
    DST = u_.v; }

#define DO_MT(MT) { \
    floatx4 c_ = {cv[MT].x, cv[MT].y, cv[MT].z, cv[MT].w}; \
    c_ = MFMA16(AF##MT##0, b0, c_); \
    c_ = MFMA16(AF##MT##1, b1, c_); \
    c_ = MFMA16(AF##MT##2, b2, c_); \
    c_ = MFMA16(AF##MT##3, b3, c_); \
    d[MT] = c_; }

#define WB_MT(MT) { \
    union { uint2 u2; __hip_bfloat16 h[4]; } pk_; \
    pk_.h[0] = __float2bfloat16(d[MT][0]); pk_.h[1] = __float2bfloat16(d[MT][1]); \
    pk_.h[2] = __float2bfloat16(d[MT][2]); pk_.h[3] = __float2bfloat16(d[MT][3]); \
    *(uint2*)(hbuf + m * HS + (MT) * 32 + q * 8) = pk_.u2; }

__global__ __launch_bounds__(64, 1) void recur_mfma(
    const float* __restrict__ v, const float* __restrict__ A,
    float* __restrict__ out)
{
    const int lane  = threadIdx.x;   // one wave per block
    const int q     = lane >> 4;     // quad 0..3
    const int m     = lane & 15;     // A-row-in-tile / batch column
    const int chunk = blockIdx.x;    // 0..127

    __shared__ uint hbuf_u[16 * HS / 4];
    char* hbuf = (char*)hbuf_u;

    // zero h state (warm start)
#pragma unroll
    for (int i = lane; i < 16 * HS / 4; i += 64) hbuf_u[i] = 0;

    // A fragments -> 32 named bf16x8 (128 regs, MFMA-operand class)
    bf16x8 AF00, AF01, AF02, AF03, AF10, AF11, AF12, AF13;
    bf16x8 AF20, AF21, AF22, AF23, AF30, AF31, AF32, AF33;
    bf16x8 AF40, AF41, AF42, AF43, AF50, AF51, AF52, AF53;
    bf16x8 AF60, AF61, AF62, AF63, AF70, AF71, AF72, AF73;
    LOADAF(0,0,AF00) LOADAF(0,1,AF01) LOADAF(0,2,AF02) LOADAF(0,3,AF03)
    LOADAF(1,0,AF10) LOADAF(1,1,AF11) LOADAF(1,2,AF12) LOADAF(1,3,AF13)
    LOADAF(2,0,AF20) LOADAF(2,1,AF21) LOADAF(2,2,AF22) LOADAF(2,3,AF23)
    LOADAF(3,0,AF30) LOADAF(3,1,AF31) LOADAF(3,2,AF32) LOADAF(3,3,AF33)
    LOADAF(4,0,AF40) LOADAF(4,1,AF41) LOADAF(4,2,AF42) LOADAF(4,3,AF43)
    LOADAF(5,0,AF50) LOADAF(5,1,AF51) LOADAF(5,2,AF52) LOADAF(5,3,AF53)
    LOADAF(6,0,AF60) LOADAF(6,1,AF61) LOADAF(6,2,AF62) LOADAF(6,3,AF63)
    LOADAF(7,0,AF70) LOADAF(7,1,AF71) LOADAF(7,2,AF72) LOADAF(7,3,AF73)

    const int tout = chunk * CHUNK_L;
    const int ts   = (tout - WARM_K < 0) ? 0 : tout - WARM_K;
    const int tend = tout + CHUNK_L;

    // v C-operand: lane (q,m) needs v[t, b=m, h=mt*16+q*4 .. +3]
    float4 cv[8], nv[8];
#pragma unroll
    for (int mt = 0; mt < 8; ++mt)
        cv[mt] = *(const float4*)(v + ((size_t)ts * B_DIM + m) * H_DIM + mt * 16 + q * 4);

#pragma unroll 2
    for (int t = ts; t < tend; ++t) {
        if (t + 1 < tend) {
#pragma unroll
            for (int mt = 0; mt < 8; ++mt)
                nv[mt] = *(const float4*)(v + ((size_t)(t + 1) * B_DIM + m) * H_DIM + mt * 16 + q * 4);
        }

        // B-operand frags: lane (q, n=m) reads h[k = kt*32+q*8 .. +7][n] (contig bf16)
        const int boff = m * HS + q * 16;
        const bf16x8 b0 = *(const bf16x8*)(hbuf + boff);
        const bf16x8 b1 = *(const bf16x8*)(hbuf + boff + 64);
        const bf16x8 b2 = *(const bf16x8*)(hbuf + boff + 128);
        const bf16x8 b3 = *(const bf16x8*)(hbuf + boff + 192);

        floatx4 d[8];
        DO_MT(0) DO_MT(1) DO_MT(2) DO_MT(3)
        DO_MT(4) DO_MT(5) DO_MT(6) DO_MT(7)

        // h' -> LDS in [batch][k] bf16 layout (rows q*4..q*4+3 of tile MT, batch m)
        WB_MT(0) WB_MT(1) WB_MT(2) WB_MT(3)
        WB_MT(4) WB_MT(5) WB_MT(6) WB_MT(7)

        if (t >= tout) {
            const size_t ob = ((size_t)t * B_DIM + m) * H_DIM;
#pragma unroll
            for (int mt = 0; mt < 8; ++mt) {
                float4 f;
                f.x = d[mt][0]; f.y = d[mt][1]; f.z = d[mt][2]; f.w = d[mt][3];
                *(float4*)(out + ob + mt * 16 + q * 4) = f;
            }
        }

#pragma unroll
        for (int mt = 0; mt < 8; ++mt) cv[mt] = nv[mt];
    }
}

// ------------------------------------------------------------------------------

extern "C" void kernel_launch(void* const* d_in, const int* in_sizes, int n_in,
                              void* d_out, int out_size, void* d_ws, size_t ws_size,
                              hipStream_t stream) {
    const float* x  = (const float*)d_in[0];
    const float* Uw = (const float*)d_in[1];
    const float* Ub = (const float*)d_in[2];
    const float* Bw = (const float*)d_in[3];
    const float* Bb = (const float*)d_in[4];
    const float* Aw = (const float*)d_in[5];
    float* out = (float*)d_out;
    float* vbuf = (float*)d_ws;   // T*B*H fp32 = 32 MiB

    gemm_gates<<<M_DIM / BM, 512, 0, stream>>>(x, Uw, Ub, Bw, Bb, vbuf);
    recur_mfma<<<T_DIM / CHUNK_L, 64, 0, stream>>>(vbuf, Aw, out);
}